// Round 9
// baseline (1790.033 us; speedup 1.0000x reference)
//
#include <hip/hip_runtime.h>
#include <math.h>

typedef _Float16 f16;
typedef f16 f16x8 __attribute__((ext_vector_type(8)));
typedef float f32x4 __attribute__((ext_vector_type(4)));

#define EPS_F16 0.0009765625f   // jnp.finfo(float16).eps

// B=8, N=2048, C=2048, H=16, D=128, M=B*N=16384, K=C=2048

// ---------------- fp32 -> fp16 cast, 8 elems/thread ----------------
__global__ __launch_bounds__(256) void k_cast8h(const float* __restrict__ in,
                                                f16* __restrict__ out,
                                                long long n8) {
  long long i = (long long)blockIdx.x * blockDim.x + threadIdx.x;
  if (i >= n8) return;
  const float4* in4 = (const float4*)in;
  float4 a = in4[i * 2];
  float4 b = in4[i * 2 + 1];
  f16x8 o;
  o[0] = (f16)a.x; o[1] = (f16)a.y; o[2] = (f16)a.z; o[3] = (f16)a.w;
  o[4] = (f16)b.x; o[5] = (f16)b.y; o[6] = (f16)b.z; o[7] = (f16)b.w;
  *(f16x8*)(out + i * 8) = o;
}

// ---------------- async global->LDS helper ----------------
__device__ __forceinline__ void gl2lds16(const void* g, void* l) {
  __builtin_amdgcn_global_load_lds(
      (const __attribute__((address_space(1))) void*)g,
      (__attribute__((address_space(3))) void*)l, 16, 0, 0);
}

// full drain + scheduling fence + barrier (explicit: do NOT trust the
// compiler's pre-barrier waitcnt insertion for runtime-addressed LDS-DMA)
__device__ __forceinline__ void drain_barrier() {
  asm volatile("s_waitcnt vmcnt(0) lgkmcnt(0)" ::: "memory");
  __builtin_amdgcn_sched_barrier(0);
  __syncthreads();
}

// ====== 256x256 GEMM, BK=32, 2-slot LDS dbuf (64KB total -> 2 blocks/CU) =====
// C = A (MxK) * Bm (NxK)^T, fp16 in. K=2048. Grid must be dim3(8, 64).
// st_16x32 XOR swizzle on LDS (zero bank conflicts, verified r5-r8).
// Drain-barrier schedule (proven race-free r5/r6); latency hidden by the
// co-resident second block per CU (m114 cross-block MFMA/stage overlap).
// MODE 0: Cout (fp32) row-major M x 2048          [final projection]
// MODE 1: Wout (fp16) (B,H,N,D) via LDS-transposed 128B-coalesced stores
//         + fused chunk partials of q^2 -> psum (q = fp16(w), scans exact in q)
template <int MODE>
__global__ __launch_bounds__(512, 4) void gemm256(const f16* __restrict__ A,
                                                  const f16* __restrict__ Bm,
                                                  float* __restrict__ Cout,
                                                  f16* __restrict__ Wout,
                                                  float* __restrict__ psum) {
  constexpr int K = 2048;
  constexpr int NT = K / 32;          // 64 K-tiles
  __shared__ alignas(16) char lds[65536];   // 2 slots x (A 16KB + B 16KB)
  const int t = threadIdx.x;
  const int lane = t & 63;
  const int wid = t >> 6;
  const int wm = wid >> 2;   // M-half owner (0..1)
  const int wn = wid & 3;    // N-quarter owner (0..3)

  // T1: XCD-aware chunked swizzle (bijective: 512 % 8 == 0)
  const int lin = blockIdx.y * 8 + blockIdx.x;     // gridDim.x == 8
  const int logical = (lin & 7) * 64 + (lin >> 3);
  const size_t bm = (size_t)(logical >> 3) * 256;
  const size_t bn = (size_t)(logical & 7) * 256;

  // staging source geometry (BK=32): thread t, chunk j in {0,1} writes LDS bytes
  // [j*8192 + t*16, +16) of the 16KB matrix region; source = involution image.
  const int sk = ((t & 3) * 8) ^ (((t >> 5) & 1) << 4);
  size_t aOff[2], bOff[2];
#pragma unroll
  for (int j = 0; j < 2; ++j) {
    int sr = j * 128 + (t >> 6) * 16 + ((t & 63) >> 2);
    aOff[j] = (bm + (size_t)sr) * K + sk;
    bOff[j] = (bn + (size_t)sr) * K + sk;
  }
  const int t16 = t * 16;

  // per-lane fragment byte offset within a 1024B subtile (same XOR involution)
  const int lbyte = (((lane & 15) * 64 + (lane >> 4) * 16) ^ ((lane & 8) << 2));

  f32x4 acc[8][4] = {};

  auto stage_tile = [&](int kt) {
    char* base = lds + (kt & 1) * 32768;
    const size_t ko = (size_t)kt * 32;
#pragma unroll
    for (int j = 0; j < 2; ++j) {
      gl2lds16(A + aOff[j] + ko, base + j * 8192 + t16);
      gl2lds16(Bm + bOff[j] + ko, base + 16384 + j * 8192 + t16);
    }
  };

  auto compute_tile = [&](int slot) {
    const char* Ab = lds + slot * 32768 + wm * 8192 + lbyte;
    const char* Bb = lds + slot * 32768 + 16384 + wn * 4096 + lbyte;
    f16x8 bfr[4];
#pragma unroll
    for (int fj = 0; fj < 4; ++fj) bfr[fj] = *(const f16x8*)(Bb + fj * 1024);
#pragma unroll
    for (int q = 0; q < 4; ++q) {
      f16x8 af0 = *(const f16x8*)(Ab + (q * 2) * 1024);
      f16x8 af1 = *(const f16x8*)(Ab + (q * 2 + 1) * 1024);
      __builtin_amdgcn_s_setprio(1);
#pragma unroll
      for (int fj = 0; fj < 4; ++fj) {
        acc[q * 2][fj] = __builtin_amdgcn_mfma_f32_16x16x32_f16(
            af0, bfr[fj], acc[q * 2][fj], 0, 0, 0);
        acc[q * 2 + 1][fj] = __builtin_amdgcn_mfma_f32_16x16x32_f16(
            af1, bfr[fj], acc[q * 2 + 1][fj], 0, 0, 0);
      }
      __builtin_amdgcn_s_setprio(0);
    }
  };

  // prologue: stage tile 0 into slot 0
  stage_tile(0);
  drain_barrier();

  for (int kt = 0; kt < NT; ++kt) {
    if (kt + 1 < NT) stage_tile(kt + 1);   // prefetch into the other slot
    compute_tile(kt & 1);
    drain_barrier();   // prefetch landed + all reads of slot kt&1 done
  }

  // ---- epilogue ----
  const int col = lane & 15;
  const int rb = (lane >> 4) * 4;
  if constexpr (MODE == 0) {
#pragma unroll
    for (int fi = 0; fi < 8; ++fi)
#pragma unroll
      for (int fj = 0; fj < 4; ++fj)
#pragma unroll
        for (int r = 0; r < 4; ++r) {
          size_t gr = bm + wm * 128 + fi * 16 + rb + r;   // row in (B*N)
          size_t gc = bn + wn * 64 + fj * 16 + col;       // out channel
          Cout[gr * 2048 + gc] = acc[fi][fj][r];
        }
  } else {
    // Quantize to fp16, stash in wave-private 8KB LDS (XOR-swizzled), read back
    // f16x8 -> 128B-coalesced stores. Two 64-row half-passes (fits 64KB LDS).
    float ssv[4] = {0.f, 0.f, 0.f, 0.f};
    char* W = lds + wid * 8192;
    const int hh = (int)(bn >> 7) + (wn >> 1);
#pragma unroll
    for (int half = 0; half < 2; ++half) {
      if (half == 1) {   // previous half's reads must finish before overwrite
        asm volatile("s_waitcnt lgkmcnt(0)" ::: "memory");
        __builtin_amdgcn_sched_barrier(0);
      }
#pragma unroll
      for (int fj = 0; fj < 4; ++fj)
#pragma unroll
        for (int fl = 0; fl < 4; ++fl)
#pragma unroll
          for (int r = 0; r < 4; ++r) {
            int row_l = fl * 16 + rb + r;           // 0..63
            int d_l = fj * 16 + col;                // 0..63
            f16 q = (f16)acc[half * 4 + fl][fj][r];
            *(f16*)(W + row_l * 128 +
                    ((d_l * 2) ^ (((row_l >> 2) & 3) << 5))) = q;
            float qf = (float)q;
            ssv[fj] += qf * qf;
          }
      asm volatile("s_waitcnt lgkmcnt(0)" ::: "memory");
      __builtin_amdgcn_sched_barrier(0);
      // address XOR compensates the stored involution: block read at physical
      // (c_p*16)^(g2<<5) IS logical d = c_p*8..+7  (verified r8)
#pragma unroll
      for (int it = 0; it < 8; ++it) {
        int row_l = it * 8 + (lane >> 3);           // 0..63
        int g2 = (row_l >> 2) & 3;
        int c_p = lane & 7;
        f16x8 v = *(const f16x8*)(W + row_l * 128 + ((c_p * 16) ^ (g2 << 5)));
        size_t gr = bm + wm * 128 + half * 64 + row_l;
        int d = (wn & 1) * 64 + c_p * 8;
        *(f16x8*)(Wout + (((gr >> 11) * 16 + hh) * 2048 + (gr & 2047)) * 128 +
                  d) = v;
      }
    }
    // fused chunk partials of q^2 (this wave's 128 rows = one chunk of n's)
#pragma unroll
    for (int fj = 0; fj < 4; ++fj) {
      float ss = ssv[fj];
      ss += __shfl_xor(ss, 16);
      ss += __shfl_xor(ss, 32);
      if (lane < 16) {
        int b = (int)(bm >> 11);
        int chunk = (int)((bm & 2047) >> 7) + wm;
        int d = (wn & 1) * 64 + fj * 16 + lane;
        psum[(((size_t)(b * 16 + hh)) * 16 + chunk) * 128 + d] = ss;
      }
    }
  }
}

// XOR-swizzled LDS index (64KB tile, conflict-free both phases)
__device__ __forceinline__ int swz(int i, int j) { return i * 128 + (j ^ (i & 31)); }

// replay chunk scan with inline exclusive prefix of raw psum (chunks < mine):
// ratio = q^2/max(cum,eps); tmp[b,h,n] = (sum_d ratio + D*bias)*temp
__global__ __launch_bounds__(128) void k_tmp(const f16* __restrict__ w,
                                             const float* __restrict__ psum,
                                             const float* __restrict__ dbias,
                                             const float* __restrict__ temp,
                                             float* __restrict__ tmp) {
  __shared__ float ratio[128 * 128];
  int blk = blockIdx.x;
  int bh = blk >> 4, chunk = blk & 15;
  int h = bh & 15;
  int d = threadIdx.x;
  float cum = 0.f;
  for (int c = 0; c < chunk; ++c)
    cum += psum[((size_t)bh * 16 + c) * 128 + d];
  const f16* base =
      w + ((size_t)bh * 2048 + (size_t)chunk * 128) * 128 + d;
  for (int i = 0; i < 128; ++i) {
    float v = (float)base[(size_t)i * 128];
    float sq = v * v;
    cum += sq;
    float dn = fmaxf(cum, EPS_F16);
    ratio[swz(i, d)] = sq / dn;
  }
  __syncthreads();
  float s = 0.f;
#pragma unroll 8
  for (int j = 0; j < 128; ++j) s += ratio[swz(d, j)];
  int n = chunk * 128 + d;
  tmp[(size_t)bh * 2048 + n] = (s + 128.f * dbias[h * 2048 + n]) * temp[h];
}

// softmax over H=16 heads. 16384 threads, one per (b,n).
__global__ __launch_bounds__(256) void k_softmax(const float* __restrict__ tmp,
                                                 float* __restrict__ Pi) {
  int idx = blockIdx.x * 256 + threadIdx.x;  // b*2048 + n
  int b = idx >> 11, n = idx & 2047;
  float v[16];
  float mx = -1e30f;
#pragma unroll
  for (int h = 0; h < 16; ++h) {
    v[h] = tmp[((size_t)(b * 16 + h)) * 2048 + n];
    mx = fmaxf(mx, v[h]);
  }
  float s = 0.f;
#pragma unroll
  for (int h = 0; h < 16; ++h) {
    v[h] = expf(v[h] - mx);
    s += v[h];
  }
  float inv = 1.f / s;
#pragma unroll
  for (int h = 0; h < 16; ++h)
    Pi[((size_t)(b * 16 + h)) * 2048 + n] = v[h] * inv;
}

// pass C: chunk partials of q^2*Pi (per d) and Pi (scalar)
__global__ __launch_bounds__(128) void k_partial2(const f16* __restrict__ w,
                                                  const float* __restrict__ Pi,
                                                  float* __restrict__ psum,
                                                  float* __restrict__ pisum) {
  int blk = blockIdx.x;
  int bh = blk >> 4, chunk = blk & 15;
  int d = threadIdx.x;
  const f16* base =
      w + ((size_t)bh * 2048 + (size_t)chunk * 128) * 128 + d;
  const float* pib = Pi + (size_t)bh * 2048 + (size_t)chunk * 128;
  float s = 0.f, sp = 0.f;
#pragma unroll 4
  for (int i = 0; i < 128; ++i) {
    float p = pib[i];
    float v = (float)base[(size_t)i * 128];
    s += v * v * p;
    sp += p;
  }
  psum[(size_t)blk * 128 + d] = s;
  if (d == 0) pisum[blk] = sp;
}

// replay with inline exclusive prefixes of raw psum2/pisum:
// dots = cum(q^2*Pi)/(cum(Pi)+eps); y = -(q*Pi)/(1+dots), fp16, (B,N,C)
__global__ __launch_bounds__(128) void k_y(const f16* __restrict__ w,
                                           const float* __restrict__ Pi,
                                           const float* __restrict__ psum2,
                                           const float* __restrict__ pisum,
                                           f16* __restrict__ yout) {
  int blk = blockIdx.x;
  int bh = blk >> 4, chunk = blk & 15;
  int b = bh >> 4, h = bh & 15;
  int d = threadIdx.x;
  float cum = 0.f, cpi = 0.f;
  for (int c = 0; c < chunk; ++c) {
    cum += psum2[((size_t)bh * 16 + c) * 128 + d];
    cpi += pisum[bh * 16 + c];
  }
  const f16* base =
      w + ((size_t)bh * 2048 + (size_t)chunk * 128) * 128 + d;
  const float* pib = Pi + (size_t)bh * 2048 + (size_t)chunk * 128;
  for (int i = 0; i < 128; ++i) {
    float p = pib[i];
    float v = (float)base[(size_t)i * 128];
    cum += v * v * p;
    cpi += p;
    float dots = cum / (cpi + EPS_F16);
    float attn = 1.f / (1.f + dots);
    float y = -(v * p) * attn;
    int n = chunk * 128 + i;
    yout[((size_t)(b * 2048 + n)) * 2048 + h * 128 + d] = (f16)y;
  }
}

// ---------------- launcher ----------------
extern "C" void kernel_launch(void* const* d_in, const int* in_sizes, int n_in,
                              void* d_out, int out_size, void* d_ws, size_t ws_size,
                              hipStream_t stream) {
  const float* x     = (const float*)d_in[0];
  const float* Wa    = (const float*)d_in[1];
  const float* Wp    = (const float*)d_in[2];
  const float* temp  = (const float*)d_in[3];
  const float* dbias = (const float*)d_in[4];
  float* out = (float*)d_out;

  char* ws = (char*)d_ws;
  // workspace layout (bytes)
  constexpr size_t OFF_W   = 0;                        // w fp16 (B,H,N,D): 67108864
  constexpr size_t OFF_XH  = 67108864;                 // x fp16 (reused as y fp16): 67108864
  constexpr size_t OFF_WAH = OFF_XH + 67108864;        // W_attn fp16: 8388608
  constexpr size_t OFF_WPB = OFF_WAH + 8388608;        // W_proj fp16: 8388608
  constexpr size_t OFF_TMP = OFF_WPB + 8388608;        // tmp (B,H,N) fp32
  constexpr size_t OFF_PI  = OFF_TMP + 2097152;        // Pi  (B,H,N) fp32
  constexpr size_t OFF_PS  = OFF_PI + 2097152;         // chunk partials
  constexpr size_t OFF_PIS = OFF_PS + 1048576;         // Pi chunk partials

  f16*   w    = (f16*)(ws + OFF_W);
  f16*   xh   = (f16*)(ws + OFF_XH);   // later reused as y (fp16)
  f16*   Wah  = (f16*)(ws + OFF_WAH);
  f16*   Wpb  = (f16*)(ws + OFF_WPB);
  float* tmp  = (float*)(ws + OFF_TMP);
  float* Pi   = (float*)(ws + OFF_PI);
  float* psum = (float*)(ws + OFF_PS);
  float* pis  = (float*)(ws + OFF_PIS);

  // casts
  k_cast8h<<<16384, 256, 0, stream>>>(x, xh, 4194304LL);
  k_cast8h<<<2048, 256, 0, stream>>>(Wa, Wah, 524288LL);
  k_cast8h<<<2048, 256, 0, stream>>>(Wp, Wpb, 524288LL);

  // GEMM1 (fp16, 256^2, 2-slot dbuf, 2 blocks/CU): w = fp16(x @ W_attn^T)
  gemm256<1><<<dim3(8, 64), 512, 0, stream>>>(xh, Wah, nullptr, w, psum);

  // scan A (prefix folded into k_tmp)
  k_tmp<<<2048, 128, 0, stream>>>(w, psum, dbias, temp, tmp);

  // softmax over heads
  k_softmax<<<64, 256, 0, stream>>>(tmp, Pi);

  // scan C: partials, then replay with inline prefix -> y (fp16, reuses xh)
  k_partial2<<<2048, 128, 0, stream>>>(w, Pi, psum, pis);
  k_y<<<2048, 128, 0, stream>>>(w, Pi, psum, pis, xh);

  // GEMM2 (fp16, 256^2, 2-slot dbuf, 2 blocks/CU): out = y @ W_proj^T
  gemm256<0><<<dim3(8, 64), 512, 0, stream>>>(xh, Wpb, out, nullptr, nullptr);
}

// Round 10
// 451.787 us; speedup vs baseline: 3.9621x; 3.9621x over previous
//
#include <hip/hip_runtime.h>
#include <math.h>

typedef _Float16 f16;
typedef f16 f16x8 __attribute__((ext_vector_type(8)));
typedef float f32x4 __attribute__((ext_vector_type(4)));

#define EPS_F16 0.0009765625f   // jnp.finfo(float16).eps

// B=8, N=2048, C=2048, H=16, D=128, M=B*N=16384, K=C=2048

// ---------------- fp32 -> fp16 cast, 8 elems/thread ----------------
__global__ __launch_bounds__(256) void k_cast8h(const float* __restrict__ in,
                                                f16* __restrict__ out,
                                                long long n8) {
  long long i = (long long)blockIdx.x * blockDim.x + threadIdx.x;
  if (i >= n8) return;
  const float4* in4 = (const float4*)in;
  float4 a = in4[i * 2];
  float4 b = in4[i * 2 + 1];
  f16x8 o;
  o[0] = (f16)a.x; o[1] = (f16)a.y; o[2] = (f16)a.z; o[3] = (f16)a.w;
  o[4] = (f16)b.x; o[5] = (f16)b.y; o[6] = (f16)b.z; o[7] = (f16)b.w;
  *(f16x8*)(out + i * 8) = o;
}

// ---------------- async global->LDS helper ----------------
__device__ __forceinline__ void gl2lds16(const void* g, void* l) {
  __builtin_amdgcn_global_load_lds(
      (const __attribute__((address_space(1))) void*)g,
      (__attribute__((address_space(3))) void*)l, 16, 0, 0);
}

// full drain + scheduling fence + barrier (explicit: do NOT trust the
// compiler's pre-barrier waitcnt insertion for runtime-addressed LDS-DMA)
__device__ __forceinline__ void drain_barrier() {
  asm volatile("s_waitcnt vmcnt(0) lgkmcnt(0)" ::: "memory");
  __builtin_amdgcn_sched_barrier(0);
  __syncthreads();
}

// ====== 256x256 GEMM, BK=32, 2-slot LDS dbuf (64KB total -> 2 blocks/CU) =====
// C = A (MxK) * Bm (NxK)^T, fp16 in. K=2048. Grid must be dim3(8, 64).
// st_16x32 XOR swizzle on LDS (zero bank conflicts, verified r5-r8).
// Drain-barrier schedule (proven race-free r5/r6); latency hidden by the
// co-resident second block per CU (m114 cross-block MFMA/stage overlap).
// NOTE launch_bounds MUST stay (512, 2): min-waves/EU=4 caps VGPR at 128 and
// spills the 128-VGPR accumulator (r9: 6x regression, FETCH 98MB->1.6GB).
// With (512,2) the compiler's ~104 VGPR already allows 4 waves/EU, so the
// 64KB LDS gives 2 blocks/CU naturally.
// MODE 0: Cout (fp32) row-major M x 2048          [final projection]
// MODE 1: Wout (fp16) (B,H,N,D) via LDS-transposed 128B-coalesced stores
//         + fused chunk partials of q^2 -> psum (q = fp16(w), scans exact in q)
template <int MODE>
__global__ __launch_bounds__(512, 2) void gemm256(const f16* __restrict__ A,
                                                  const f16* __restrict__ Bm,
                                                  float* __restrict__ Cout,
                                                  f16* __restrict__ Wout,
                                                  float* __restrict__ psum) {
  constexpr int K = 2048;
  constexpr int NT = K / 32;          // 64 K-tiles
  __shared__ alignas(16) char lds[65536];   // 2 slots x (A 16KB + B 16KB)
  const int t = threadIdx.x;
  const int lane = t & 63;
  const int wid = t >> 6;
  const int wm = wid >> 2;   // M-half owner (0..1)
  const int wn = wid & 3;    // N-quarter owner (0..3)

  // T1: XCD-aware chunked swizzle (bijective: 512 % 8 == 0)
  const int lin = blockIdx.y * 8 + blockIdx.x;     // gridDim.x == 8
  const int logical = (lin & 7) * 64 + (lin >> 3);
  const size_t bm = (size_t)(logical >> 3) * 256;
  const size_t bn = (size_t)(logical & 7) * 256;

  // staging source geometry (BK=32): thread t, chunk j in {0,1} writes LDS bytes
  // [j*8192 + t*16, +16) of the 16KB matrix region; source = involution image.
  const int sk = ((t & 3) * 8) ^ (((t >> 5) & 1) << 4);
  size_t aOff[2], bOff[2];
#pragma unroll
  for (int j = 0; j < 2; ++j) {
    int sr = j * 128 + (t >> 6) * 16 + ((t & 63) >> 2);
    aOff[j] = (bm + (size_t)sr) * K + sk;
    bOff[j] = (bn + (size_t)sr) * K + sk;
  }
  const int t16 = t * 16;

  // per-lane fragment byte offset within a 1024B subtile (same XOR involution)
  const int lbyte = (((lane & 15) * 64 + (lane >> 4) * 16) ^ ((lane & 8) << 2));

  f32x4 acc[8][4] = {};

  auto stage_tile = [&](int kt) {
    char* base = lds + (kt & 1) * 32768;
    const size_t ko = (size_t)kt * 32;
#pragma unroll
    for (int j = 0; j < 2; ++j) {
      gl2lds16(A + aOff[j] + ko, base + j * 8192 + t16);
      gl2lds16(Bm + bOff[j] + ko, base + 16384 + j * 8192 + t16);
    }
  };

  auto compute_tile = [&](int slot) {
    const char* Ab = lds + slot * 32768 + wm * 8192 + lbyte;
    const char* Bb = lds + slot * 32768 + 16384 + wn * 4096 + lbyte;
    f16x8 bfr[4];
#pragma unroll
    for (int fj = 0; fj < 4; ++fj) bfr[fj] = *(const f16x8*)(Bb + fj * 1024);
#pragma unroll
    for (int q = 0; q < 4; ++q) {
      f16x8 af0 = *(const f16x8*)(Ab + (q * 2) * 1024);
      f16x8 af1 = *(const f16x8*)(Ab + (q * 2 + 1) * 1024);
      __builtin_amdgcn_s_setprio(1);
#pragma unroll
      for (int fj = 0; fj < 4; ++fj) {
        acc[q * 2][fj] = __builtin_amdgcn_mfma_f32_16x16x32_f16(
            af0, bfr[fj], acc[q * 2][fj], 0, 0, 0);
        acc[q * 2 + 1][fj] = __builtin_amdgcn_mfma_f32_16x16x32_f16(
            af1, bfr[fj], acc[q * 2 + 1][fj], 0, 0, 0);
      }
      __builtin_amdgcn_s_setprio(0);
    }
  };

  // prologue: stage tile 0 into slot 0
  stage_tile(0);
  drain_barrier();

  for (int kt = 0; kt < NT; ++kt) {
    if (kt + 1 < NT) stage_tile(kt + 1);   // prefetch into the other slot
    compute_tile(kt & 1);
    drain_barrier();   // prefetch landed + all reads of slot kt&1 done
  }

  // ---- epilogue ----
  const int col = lane & 15;
  const int rb = (lane >> 4) * 4;
  if constexpr (MODE == 0) {
#pragma unroll
    for (int fi = 0; fi < 8; ++fi)
#pragma unroll
      for (int fj = 0; fj < 4; ++fj)
#pragma unroll
        for (int r = 0; r < 4; ++r) {
          size_t gr = bm + wm * 128 + fi * 16 + rb + r;   // row in (B*N)
          size_t gc = bn + wn * 64 + fj * 16 + col;       // out channel
          Cout[gr * 2048 + gc] = acc[fi][fj][r];
        }
  } else {
    // Quantize to fp16, stash in wave-private 8KB LDS (XOR-swizzled), read back
    // f16x8 -> 128B-coalesced stores. Two 64-row half-passes (fits 64KB LDS).
    float ssv[4] = {0.f, 0.f, 0.f, 0.f};
    char* W = lds + wid * 8192;
    const int hh = (int)(bn >> 7) + (wn >> 1);
#pragma unroll
    for (int half = 0; half < 2; ++half) {
      if (half == 1) {   // previous half's reads must finish before overwrite
        asm volatile("s_waitcnt lgkmcnt(0)" ::: "memory");
        __builtin_amdgcn_sched_barrier(0);
      }
#pragma unroll
      for (int fj = 0; fj < 4; ++fj)
#pragma unroll
        for (int fl = 0; fl < 4; ++fl)
#pragma unroll
          for (int r = 0; r < 4; ++r) {
            int row_l = fl * 16 + rb + r;           // 0..63
            int d_l = fj * 16 + col;                // 0..63
            f16 q = (f16)acc[half * 4 + fl][fj][r];
            *(f16*)(W + row_l * 128 +
                    ((d_l * 2) ^ (((row_l >> 2) & 3) << 5))) = q;
            float qf = (float)q;
            ssv[fj] += qf * qf;
          }
      asm volatile("s_waitcnt lgkmcnt(0)" ::: "memory");
      __builtin_amdgcn_sched_barrier(0);
      // address XOR compensates the stored involution: block read at physical
      // (c_p*16)^(g2<<5) IS logical d = c_p*8..+7  (verified r8)
#pragma unroll
      for (int it = 0; it < 8; ++it) {
        int row_l = it * 8 + (lane >> 3);           // 0..63
        int g2 = (row_l >> 2) & 3;
        int c_p = lane & 7;
        f16x8 v = *(const f16x8*)(W + row_l * 128 + ((c_p * 16) ^ (g2 << 5)));
        size_t gr = bm + wm * 128 + half * 64 + row_l;
        int d = (wn & 1) * 64 + c_p * 8;
        *(f16x8*)(Wout + (((gr >> 11) * 16 + hh) * 2048 + (gr & 2047)) * 128 +
                  d) = v;
      }
    }
    // fused chunk partials of q^2 (this wave's 128 rows = one chunk of n's)
#pragma unroll
    for (int fj = 0; fj < 4; ++fj) {
      float ss = ssv[fj];
      ss += __shfl_xor(ss, 16);
      ss += __shfl_xor(ss, 32);
      if (lane < 16) {
        int b = (int)(bm >> 11);
        int chunk = (int)((bm & 2047) >> 7) + wm;
        int d = (wn & 1) * 64 + fj * 16 + lane;
        psum[(((size_t)(b * 16 + hh)) * 16 + chunk) * 128 + d] = ss;
      }
    }
  }
}

// XOR-swizzled LDS index (64KB tile, conflict-free both phases)
__device__ __forceinline__ int swz(int i, int j) { return i * 128 + (j ^ (i & 31)); }

// replay chunk scan with inline exclusive prefix of raw psum (chunks < mine):
// ratio = q^2/max(cum,eps); tmp[b,h,n] = (sum_d ratio + D*bias)*temp
__global__ __launch_bounds__(128) void k_tmp(const f16* __restrict__ w,
                                             const float* __restrict__ psum,
                                             const float* __restrict__ dbias,
                                             const float* __restrict__ temp,
                                             float* __restrict__ tmp) {
  __shared__ float ratio[128 * 128];
  int blk = blockIdx.x;
  int bh = blk >> 4, chunk = blk & 15;
  int h = bh & 15;
  int d = threadIdx.x;
  float cum = 0.f;
  for (int c = 0; c < chunk; ++c)
    cum += psum[((size_t)bh * 16 + c) * 128 + d];
  const f16* base =
      w + ((size_t)bh * 2048 + (size_t)chunk * 128) * 128 + d;
  for (int i = 0; i < 128; ++i) {
    float v = (float)base[(size_t)i * 128];
    float sq = v * v;
    cum += sq;
    float dn = fmaxf(cum, EPS_F16);
    ratio[swz(i, d)] = sq / dn;
  }
  __syncthreads();
  float s = 0.f;
#pragma unroll 8
  for (int j = 0; j < 128; ++j) s += ratio[swz(d, j)];
  int n = chunk * 128 + d;
  tmp[(size_t)bh * 2048 + n] = (s + 128.f * dbias[h * 2048 + n]) * temp[h];
}

// softmax over H=16 heads. 16384 threads, one per (b,n).
__global__ __launch_bounds__(256) void k_softmax(const float* __restrict__ tmp,
                                                 float* __restrict__ Pi) {
  int idx = blockIdx.x * 256 + threadIdx.x;  // b*2048 + n
  int b = idx >> 11, n = idx & 2047;
  float v[16];
  float mx = -1e30f;
#pragma unroll
  for (int h = 0; h < 16; ++h) {
    v[h] = tmp[((size_t)(b * 16 + h)) * 2048 + n];
    mx = fmaxf(mx, v[h]);
  }
  float s = 0.f;
#pragma unroll
  for (int h = 0; h < 16; ++h) {
    v[h] = expf(v[h] - mx);
    s += v[h];
  }
  float inv = 1.f / s;
#pragma unroll
  for (int h = 0; h < 16; ++h)
    Pi[((size_t)(b * 16 + h)) * 2048 + n] = v[h] * inv;
}

// pass C: chunk partials of q^2*Pi (per d) and Pi (scalar)
__global__ __launch_bounds__(128) void k_partial2(const f16* __restrict__ w,
                                                  const float* __restrict__ Pi,
                                                  float* __restrict__ psum,
                                                  float* __restrict__ pisum) {
  int blk = blockIdx.x;
  int bh = blk >> 4, chunk = blk & 15;
  int d = threadIdx.x;
  const f16* base =
      w + ((size_t)bh * 2048 + (size_t)chunk * 128) * 128 + d;
  const float* pib = Pi + (size_t)bh * 2048 + (size_t)chunk * 128;
  float s = 0.f, sp = 0.f;
#pragma unroll 4
  for (int i = 0; i < 128; ++i) {
    float p = pib[i];
    float v = (float)base[(size_t)i * 128];
    s += v * v * p;
    sp += p;
  }
  psum[(size_t)blk * 128 + d] = s;
  if (d == 0) pisum[blk] = sp;
}

// replay with inline exclusive prefixes of raw psum2/pisum:
// dots = cum(q^2*Pi)/(cum(Pi)+eps); y = -(q*Pi)/(1+dots), fp16, (B,N,C)
__global__ __launch_bounds__(128) void k_y(const f16* __restrict__ w,
                                           const float* __restrict__ Pi,
                                           const float* __restrict__ psum2,
                                           const float* __restrict__ pisum,
                                           f16* __restrict__ yout) {
  int blk = blockIdx.x;
  int bh = blk >> 4, chunk = blk & 15;
  int b = bh >> 4, h = bh & 15;
  int d = threadIdx.x;
  float cum = 0.f, cpi = 0.f;
  for (int c = 0; c < chunk; ++c) {
    cum += psum2[((size_t)bh * 16 + c) * 128 + d];
    cpi += pisum[bh * 16 + c];
  }
  const f16* base =
      w + ((size_t)bh * 2048 + (size_t)chunk * 128) * 128 + d;
  const float* pib = Pi + (size_t)bh * 2048 + (size_t)chunk * 128;
  for (int i = 0; i < 128; ++i) {
    float p = pib[i];
    float v = (float)base[(size_t)i * 128];
    cum += v * v * p;
    cpi += p;
    float dots = cum / (cpi + EPS_F16);
    float attn = 1.f / (1.f + dots);
    float y = -(v * p) * attn;
    int n = chunk * 128 + i;
    yout[((size_t)(b * 2048 + n)) * 2048 + h * 128 + d] = (f16)y;
  }
}

// ---------------- launcher ----------------
extern "C" void kernel_launch(void* const* d_in, const int* in_sizes, int n_in,
                              void* d_out, int out_size, void* d_ws, size_t ws_size,
                              hipStream_t stream) {
  const float* x     = (const float*)d_in[0];
  const float* Wa    = (const float*)d_in[1];
  const float* Wp    = (const float*)d_in[2];
  const float* temp  = (const float*)d_in[3];
  const float* dbias = (const float*)d_in[4];
  float* out = (float*)d_out;

  char* ws = (char*)d_ws;
  // workspace layout (bytes)
  constexpr size_t OFF_W   = 0;                        // w fp16 (B,H,N,D): 67108864
  constexpr size_t OFF_XH  = 67108864;                 // x fp16 (reused as y fp16): 67108864
  constexpr size_t OFF_WAH = OFF_XH + 67108864;        // W_attn fp16: 8388608
  constexpr size_t OFF_WPB = OFF_WAH + 8388608;        // W_proj fp16: 8388608
  constexpr size_t OFF_TMP = OFF_WPB + 8388608;        // tmp (B,H,N) fp32
  constexpr size_t OFF_PI  = OFF_TMP + 2097152;        // Pi  (B,H,N) fp32
  constexpr size_t OFF_PS  = OFF_PI + 2097152;         // chunk partials
  constexpr size_t OFF_PIS = OFF_PS + 1048576;         // Pi chunk partials

  f16*   w    = (f16*)(ws + OFF_W);
  f16*   xh   = (f16*)(ws + OFF_XH);   // later reused as y (fp16)
  f16*   Wah  = (f16*)(ws + OFF_WAH);
  f16*   Wpb  = (f16*)(ws + OFF_WPB);
  float* tmp  = (float*)(ws + OFF_TMP);
  float* Pi   = (float*)(ws + OFF_PI);
  float* psum = (float*)(ws + OFF_PS);
  float* pis  = (float*)(ws + OFF_PIS);

  // casts
  k_cast8h<<<16384, 256, 0, stream>>>(x, xh, 4194304LL);
  k_cast8h<<<2048, 256, 0, stream>>>(Wa, Wah, 524288LL);
  k_cast8h<<<2048, 256, 0, stream>>>(Wp, Wpb, 524288LL);

  // GEMM1 (fp16, 256^2, 2-slot dbuf, 2 blocks/CU): w = fp16(x @ W_attn^T)
  gemm256<1><<<dim3(8, 64), 512, 0, stream>>>(xh, Wah, nullptr, w, psum);

  // scan A (prefix folded into k_tmp)
  k_tmp<<<2048, 128, 0, stream>>>(w, psum, dbias, temp, tmp);

  // softmax over heads
  k_softmax<<<64, 256, 0, stream>>>(tmp, Pi);

  // scan C: partials, then replay with inline prefix -> y (fp16, reuses xh)
  k_partial2<<<2048, 128, 0, stream>>>(w, Pi, psum, pis);
  k_y<<<2048, 128, 0, stream>>>(w, Pi, psum, pis, xh);

  // GEMM2 (fp16, 256^2, 2-slot dbuf, 2 blocks/CU): out = y @ W_proj^T
  gemm256<0><<<dim3(8, 64), 512, 0, stream>>>(xh, Wpb, out, nullptr, nullptr);
}